// Round 9
// baseline (339.112 us; speedup 1.0000x reference)
//
#include <hip/hip_runtime.h>
#include <math.h>

// Problem constants (fixed by setup_inputs)
#define NODES_TOT 7424      // 64 * 116
#define EDGES     237568    // NODES_TOT * 32
#define BATCH     64
#define NN        116
#define KDIM      7424      // FC K dim
#define N1        7424      // FC1 out
#define N2        13456     // FC2 out (116*116)
#define KQ        1856      // KDIM/4 = per-wave k-quarter
#define NSUB      29        // KQ/64 substeps per wave

typedef __attribute__((ext_vector_type(8))) short bf16x8;
typedef __attribute__((ext_vector_type(4))) float f32x4;
typedef __attribute__((ext_vector_type(4))) short s16x4;

__device__ __forceinline__ float mish_f(float v) {
    float sp = fmaxf(v, 0.0f) + log1pf(expf(-fabsf(v)));
    return v * tanhf(sp);
}

__device__ __forceinline__ unsigned short bf_rne(float f) {
    unsigned u = __float_as_uint(f);
    u += 0x7fffu + ((u >> 16) & 1u);
    return (unsigned short)(u >> 16);
}

// ---------- small utility ----------
__global__ void zero_kernel(int* __restrict__ p, int n) {
    int i = blockIdx.x * 256 + threadIdx.x;
    if (i < n) p[i] = 0;
}

// ---------- CSR build ----------
__global__ void hist_kernel(const int* __restrict__ dst, int* __restrict__ hist) {
    int e = blockIdx.x * 256 + threadIdx.x;
    if (e < EDGES) atomicAdd(&hist[dst[e]], 1);
}

__global__ void scan_kernel(const int* __restrict__ hist, int* __restrict__ row_start,
                            int* __restrict__ cursor) {
    __shared__ int s[1024];
    int t = threadIdx.x;
    int base = t * 8;
    int loc[8];
    int sum = 0;
    #pragma unroll
    for (int c = 0; c < 8; ++c) {
        int idx = base + c;
        int v = (idx < NODES_TOT) ? hist[idx] : 0;
        loc[c] = sum;
        sum += v;
    }
    s[t] = sum;
    __syncthreads();
    for (int off = 1; off < 1024; off <<= 1) {
        int v = (t >= off) ? s[t - off] : 0;
        __syncthreads();
        s[t] += v;
        __syncthreads();
    }
    int excl = s[t] - sum;
    #pragma unroll
    for (int c = 0; c < 8; ++c) {
        int idx = base + c;
        if (idx < NODES_TOT) {
            int r = excl + loc[c];
            row_start[idx] = r;
            cursor[idx] = r;
        }
    }
}

__global__ void csr_fill_kernel(const int* __restrict__ src, const int* __restrict__ dst,
                                int* __restrict__ cursor, int* __restrict__ csr_src) {
    int e = blockIdx.x * 256 + threadIdx.x;
    if (e < EDGES) {
        int p = atomicAdd(&cursor[dst[e]], 1);
        csr_src[p] = src[e];
    }
}

// ---------- fused mean-aggregate + SAGE linear + mish ----------
template <bool BF>
__global__ void __launch_bounds__(256) conv_kernel(
        const float* __restrict__ x, const int* __restrict__ csr_src,
        const int* __restrict__ row_start, const int* __restrict__ deg_arr,
        const float* __restrict__ w_l, const float* __restrict__ b_l,
        const float* __restrict__ w_r, void* __restrict__ h_out_v) {
    __shared__ float wlT[64 * 64];   // [k][f]
    __shared__ float wrT[64 * 64];   // [k][f]
    __shared__ float mv[4][64];
    __shared__ float xv[4][64];
    int t = threadIdx.x;
    for (int i = 0; i < 16; ++i) {
        int idx = t + i * 256;
        int f = idx >> 6, k = idx & 63;
        wlT[k * 64 + f] = w_l[idx];
        wrT[k * 64 + f] = w_r[idx];
    }
    int g = t >> 6, f = t & 63;
    __syncthreads();
    for (int nb = blockIdx.x * 4; nb < NODES_TOT; nb += gridDim.x * 4) {
        int node = nb + g;
        int deg = deg_arr[node];
        int rs = row_start[node];
        float sum = 0.f;
        for (int e = 0; e < deg; ++e) {
            int s = csr_src[rs + e];
            sum += x[s * 64 + f];
        }
        float mean = sum / (float)max(deg, 1);
        mv[g][f] = mean;
        xv[g][f] = x[node * 64 + f];
        __syncthreads();
        float o = b_l[f];
        #pragma unroll
        for (int k = 0; k < 64; ++k) {
            o = fmaf(mv[g][k], wlT[k * 64 + f], o);
            o = fmaf(xv[g][k], wrT[k * 64 + f], o);
        }
        float m = mish_f(o);
        if (BF) ((unsigned short*)h_out_v)[node * 64 + f] = bf_rne(m);
        else    ((float*)h_out_v)[node * 64 + f] = m;
        __syncthreads();
    }
}

// ---------- deep-K streaming bf16-MFMA GEMM ----------
// Block = 16 N-rows x full K; 4 waves = 4 k-quarters (in-block k-split, LDS-reduced).
// Each wave streams its 16 W rows at 7.4 KB fully-sequential per row, issued as
// 1 KB single-row instructions (64 lanes x 16B on ONE row) -> maximal DRAM run
// length. W regs -> bf16 -> wave-private LDS (XOR-swizzled); A (L2-resident bf16)
// prefetched per-substep into regs -> wave-private LDS. NO barriers in the main
// loop (all LDS regions wave-private); single __syncthreads before the epilogue
// k-reduction + fused bias (+mish+bf16 cast for FC1).
template <bool MISH>
__global__ void __launch_bounds__(256, 2) gemm_deep(
        const unsigned short* __restrict__ Abf, const float* __restrict__ W,
        const float* __restrict__ bias, void* __restrict__ Cout, int N) {
    __shared__ __align__(16) unsigned short WP[4][16][32][8];  // 32 KB wave-private W
    __shared__ __align__(16) unsigned short AB[4][64][8][8];   // 32 KB wave-private A
    int t = threadIdx.x;
    int wv = t >> 6, l = t & 63, l15 = l & 15, hi = l >> 4;
    int n0 = blockIdx.x * 16;
    size_t q0 = (size_t)wv * KQ;             // wave's k-quarter base

    const float* wbase = W + (size_t)n0 * KDIM + q0 + (size_t)l * 4;
    const unsigned short* abase = Abf + q0 + (size_t)(l & 7) * 8;
    int ar8 = l >> 3;                        // A row-within-octet

    f32x4 acc[4];
    #pragma unroll
    for (int g = 0; g < 4; ++g) acc[g] = (f32x4){0.f, 0.f, 0.f, 0.f};

    f32x4 w[16];     // one macro (256 k) of W: instr j = row n0+j, 1KB contiguous
    f32x4 wt[4];     // tail substep (64 k)
    bf16x8 aN[8];    // one substep of A (64 rows x 64 k)

    // ---- staging macros ----
#define IW(m) do {                                                         \
        _Pragma("unroll")                                                  \
        for (int j = 0; j < 16; ++j)                                       \
            w[j] = *(const f32x4*)(wbase + (size_t)j * KDIM + (size_t)(m) * 256); \
        __builtin_amdgcn_sched_barrier(0);                                 \
    } while (0)

#define IWT() do {                                                         \
        _Pragma("unroll")                                                  \
        for (int i = 0; i < 4; ++i)                                        \
            wt[i] = *(const f32x4*)(W + (size_t)(n0 + i * 4 + hi) * KDIM + \
                                    q0 + 1792 + (size_t)l15 * 4);          \
        __builtin_amdgcn_sched_barrier(0);                                 \
    } while (0)

#define CW() do {                                                          \
        _Pragma("unroll")                                                  \
        for (int j = 0; j < 16; ++j) {                                     \
            s16x4 cv;                                                      \
            _Pragma("unroll")                                              \
            for (int e = 0; e < 4; ++e) cv[e] = (short)bf_rne(w[j][e]);    \
            *(s16x4*)&WP[wv][j][(l >> 1) ^ ((j & 7) << 2)][(l & 1) * 4] = cv; \
        }                                                                  \
    } while (0)

#define CWT() do {                                                         \
        _Pragma("unroll")                                                  \
        for (int i = 0; i < 4; ++i) {                                      \
            s16x4 cv;                                                      \
            _Pragma("unroll")                                              \
            for (int e = 0; e < 4; ++e) cv[e] = (short)bf_rne(wt[i][e]);   \
            int r = i * 4 + hi;                                            \
            *(s16x4*)&WP[wv][r][(l15 >> 1) ^ ((r & 7) << 2)][(l & 1) * 4] = cv; \
        }                                                                  \
    } while (0)

#define IA(sg) do {                                                        \
        _Pragma("unroll")                                                  \
        for (int i = 0; i < 8; ++i)                                        \
            aN[i] = *(const bf16x8*)(abase + (size_t)(i * 8 + ar8) * KDIM + \
                                     (size_t)(sg) * 64);                   \
    } while (0)

#define DA() do {                                                          \
        _Pragma("unroll")                                                  \
        for (int i = 0; i < 8; ++i) {                                      \
            int rr = i * 8 + ar8;                                          \
            *(bf16x8*)&AB[wv][rr][(l & 7) ^ (rr & 7)][0] = aN[i];          \
        }                                                                  \
    } while (0)

#define MFMAS(s) do {                                                      \
        _Pragma("unroll")                                                  \
        for (int u = 0; u < 2; ++u) {                                      \
            int fw = u * 4 + hi;                                           \
            bf16x8 bh = *(const bf16x8*)&WP[wv][l15][((s) * 8 + fw) ^ ((l15 & 7) << 2)][0]; \
            _Pragma("unroll")                                              \
            for (int g = 0; g < 4; ++g) {                                  \
                int arr = g * 16 + l15;                                    \
                bf16x8 avv = *(const bf16x8*)&AB[wv][arr][fw ^ (arr & 7)][0]; \
                acc[g] = __builtin_amdgcn_mfma_f32_16x16x32_bf16(avv, bh, acc[g], 0, 0, 0); \
            }                                                              \
        }                                                                  \
    } while (0)

    // ---- prologue ----
    IW(0);
    IA(0);
    CW();           // waits w (macro 0), fills WP
    DA();           // waits aN (substep 0), fills AB
    IA(1);

    // ---- main loop: 7 macros x 4 substeps, no barriers ----
    for (int m = 0; m < 7; ++m) {
        if (m < 6) IW(m + 1); else IWT();
        #pragma unroll
        for (int s = 0; s < 4; ++s) {
            int sg = m * 4 + s;
            MFMAS(s);
            DA();                            // dump A(sg+1) into AB
            if (sg + 2 <= 28) IA(sg + 2);    // prefetch A(sg+2)
        }
        if (m < 6) CW(); else CWT();         // WP <- next macro / tail
    }
    MFMAS(0);                                // tail substep 28 (tail uses s=0 slots)

#undef IW
#undef IWT
#undef CW
#undef CWT
#undef IA
#undef DA
#undef MFMAS

    // ---- epilogue: in-block k-reduction + bias (+ mish + cast) ----
    __syncthreads();
    float* CS = (float*)&WP[0][0][0][0];     // 4 waves x 1024 floats = 16 KB
    #pragma unroll
    for (int g = 0; g < 4; ++g)
        #pragma unroll
        for (int rr = 0; rr < 4; ++rr) {
            int row = g * 16 + hi * 4 + rr;
            CS[wv * 1024 + row * 16 + l15] = acc[g][rr];
        }
    __syncthreads();
    {
        int row = t >> 2;                    // 0..63
        int c0 = (t & 3) * 4;                // 0,4,8,12
        f32x4 sum = *(const f32x4*)&CS[0 * 1024 + row * 16 + c0];
        sum += *(const f32x4*)&CS[1 * 1024 + row * 16 + c0];
        sum += *(const f32x4*)&CS[2 * 1024 + row * 16 + c0];
        sum += *(const f32x4*)&CS[3 * 1024 + row * 16 + c0];
        f32x4 b4 = *(const f32x4*)&bias[n0 + c0];
        if (MISH) {
            s16x4 o;
            #pragma unroll
            for (int j = 0; j < 4; ++j) o[j] = (short)bf_rne(mish_f(sum[j] + b4[j]));
            *(s16x4*)&((unsigned short*)Cout)[(size_t)row * N + n0 + c0] = o;
        } else {
            f32x4 o = sum + b4;
            *(f32x4*)&((float*)Cout)[(size_t)row * N + n0 + c0] = o;
        }
    }
}

// ---------- symmetrize + unit diagonal (C2 L2-resident, bias pre-added) ----------
__global__ void sym_kernel(const float* __restrict__ C2, float* __restrict__ out) {
    int tid = blockIdx.x * 256 + threadIdx.x;
    if (tid >= BATCH * NN * NN) return;
    int j = tid % NN;
    int r = tid / NN;
    int i = r % NN;
    int b = r / NN;
    float v;
    if (i == j) {
        v = 1.0f;
    } else {
        v = 0.5f * (C2[(size_t)b * N2 + i * NN + j] + C2[(size_t)b * N2 + j * NN + i]);
    }
    out[tid] = v;
}

extern "C" void kernel_launch(void* const* d_in, const int* in_sizes, int n_in,
                              void* d_out, int out_size, void* d_ws, size_t ws_size,
                              hipStream_t stream) {
    const float* z     = (const float*)d_in[0];
    const int*   edge  = (const int*)d_in[1];
    const float* w1_l  = (const float*)d_in[3];
    const float* b1_l  = (const float*)d_in[4];
    const float* w1_r  = (const float*)d_in[5];
    const float* w2_l  = (const float*)d_in[6];
    const float* b2_l  = (const float*)d_in[7];
    const float* w2_r  = (const float*)d_in[8];
    const float* fc1_w = (const float*)d_in[9];
    const float* fc1_b = (const float*)d_in[10];
    const float* fc2_w = (const float*)d_in[11];
    const float* fc2_b = (const float*)d_in[12];
    float* out = (float*)d_out;

    char* ws = (char*)d_ws;
    size_t off = 0;
    auto alloc = [&](size_t bytes) {
        void* p = ws + off;
        off = (off + bytes + 255) & ~(size_t)255;
        return p;
    };
    int*            hist      = (int*)alloc(NODES_TOT * 4);
    int*            row_start = (int*)alloc(NODES_TOT * 4);
    int*            cursor    = (int*)alloc(NODES_TOT * 4);
    int*            csr_src   = (int*)alloc((size_t)EDGES * 4);
    float*          h1        = (float*)alloc((size_t)NODES_TOT * 64 * 4);
    unsigned short* A1        = (unsigned short*)alloc((size_t)NODES_TOT * 64 * 2);
    unsigned short* A2        = (unsigned short*)alloc((size_t)BATCH * N1 * 2);
    float*          C2        = (float*)alloc((size_t)BATCH * N2 * 4);

    const int* src = edge;
    const int* dst = edge + EDGES;

    zero_kernel<<<(NODES_TOT + 255) / 256, 256, 0, stream>>>(hist, NODES_TOT);
    hist_kernel<<<(EDGES + 255) / 256, 256, 0, stream>>>(dst, hist);
    scan_kernel<<<1, 1024, 0, stream>>>(hist, row_start, cursor);
    csr_fill_kernel<<<(EDGES + 255) / 256, 256, 0, stream>>>(src, dst, cursor, csr_src);

    conv_kernel<false><<<928, 256, 0, stream>>>(z, csr_src, row_start, hist, w1_l, b1_l, w1_r, h1);
    conv_kernel<true><<<928, 256, 0, stream>>>(h1, csr_src, row_start, hist, w2_l, b2_l, w2_r, A1);

    // FC1: 464 blocks of 16 cols; fused reduce+bias+mish+cast epilogue -> A2 (bf16)
    gemm_deep<true><<<N1 / 16, 256, 0, stream>>>(A1, fc1_w, fc1_b, A2, N1);

    // FC2: 841 blocks of 16 cols; fused reduce+bias epilogue -> C2 (fp32)
    gemm_deep<false><<<N2 / 16, 256, 0, stream>>>(A2, fc2_w, fc2_b, C2, N2);

    sym_kernel<<<(BATCH * NN * NN + 255) / 256, 256, 0, stream>>>(C2, out);
}

// Round 10
// 332.000 us; speedup vs baseline: 1.0214x; 1.0214x over previous
//
#include <hip/hip_runtime.h>
#include <math.h>

// Problem constants (fixed by setup_inputs)
#define NODES_TOT 7424      // 64 * 116
#define EDGES     237568    // NODES_TOT * 32
#define BATCH     64
#define NN        116
#define KDIM      7424      // FC K dim
#define N1        7424      // FC1 out
#define N2        13456     // FC2 out (116*116)
#define NKB       116       // KDIM / 64 k-steps total
#define KSPLIT    8

typedef __attribute__((ext_vector_type(8))) short bf16x8;
typedef __attribute__((ext_vector_type(4))) float f32x4;
typedef __attribute__((ext_vector_type(4))) short s16x4;

__device__ __forceinline__ float mish_f(float v) {
    float sp = fmaxf(v, 0.0f) + log1pf(expf(-fabsf(v)));
    return v * tanhf(sp);
}

__device__ __forceinline__ unsigned short bf_rne(float f) {
    unsigned u = __float_as_uint(f);
    u += 0x7fffu + ((u >> 16) & 1u);
    return (unsigned short)(u >> 16);
}

__device__ __forceinline__ void gload_lds16(const void* g, void* l) {
    __builtin_amdgcn_global_load_lds(
        (const __attribute__((address_space(1))) void*)g,
        (__attribute__((address_space(3))) void*)l, 16, 0, 0);
}

// ---------- small utility ----------
__global__ void zero_kernel(int* __restrict__ p, int n) {
    int i = blockIdx.x * 256 + threadIdx.x;
    if (i < n) p[i] = 0;
}

// ---------- CSR build ----------
__global__ void hist_kernel(const int* __restrict__ dst, int* __restrict__ hist) {
    int e = blockIdx.x * 256 + threadIdx.x;
    if (e < EDGES) atomicAdd(&hist[dst[e]], 1);
}

__global__ void scan_kernel(const int* __restrict__ hist, int* __restrict__ row_start,
                            int* __restrict__ cursor) {
    __shared__ int s[1024];
    int t = threadIdx.x;
    int base = t * 8;
    int loc[8];
    int sum = 0;
    #pragma unroll
    for (int c = 0; c < 8; ++c) {
        int idx = base + c;
        int v = (idx < NODES_TOT) ? hist[idx] : 0;
        loc[c] = sum;
        sum += v;
    }
    s[t] = sum;
    __syncthreads();
    for (int off = 1; off < 1024; off <<= 1) {
        int v = (t >= off) ? s[t - off] : 0;
        __syncthreads();
        s[t] += v;
        __syncthreads();
    }
    int excl = s[t] - sum;
    #pragma unroll
    for (int c = 0; c < 8; ++c) {
        int idx = base + c;
        if (idx < NODES_TOT) {
            int r = excl + loc[c];
            row_start[idx] = r;
            cursor[idx] = r;
        }
    }
}

__global__ void csr_fill_kernel(const int* __restrict__ src, const int* __restrict__ dst,
                                int* __restrict__ cursor, int* __restrict__ csr_src) {
    int e = blockIdx.x * 256 + threadIdx.x;
    if (e < EDGES) {
        int p = atomicAdd(&cursor[dst[e]], 1);
        csr_src[p] = src[e];
    }
}

// ---------- fused mean-aggregate + SAGE linear + mish ----------
template <bool BF>
__global__ void __launch_bounds__(256) conv_kernel(
        const float* __restrict__ x, const int* __restrict__ csr_src,
        const int* __restrict__ row_start, const int* __restrict__ deg_arr,
        const float* __restrict__ w_l, const float* __restrict__ b_l,
        const float* __restrict__ w_r, void* __restrict__ h_out_v) {
    __shared__ float wlT[64 * 64];   // [k][f]
    __shared__ float wrT[64 * 64];   // [k][f]
    __shared__ float mv[4][64];
    __shared__ float xv[4][64];
    int t = threadIdx.x;
    for (int i = 0; i < 16; ++i) {
        int idx = t + i * 256;
        int f = idx >> 6, k = idx & 63;
        wlT[k * 64 + f] = w_l[idx];
        wrT[k * 64 + f] = w_r[idx];
    }
    int g = t >> 6, f = t & 63;
    __syncthreads();
    for (int nb = blockIdx.x * 4; nb < NODES_TOT; nb += gridDim.x * 4) {
        int node = nb + g;
        int deg = deg_arr[node];
        int rs = row_start[node];
        float sum = 0.f;
        for (int e = 0; e < deg; ++e) {
            int s = csr_src[rs + e];
            sum += x[s * 64 + f];
        }
        float mean = sum / (float)max(deg, 1);
        mv[g][f] = mean;
        xv[g][f] = x[node * 64 + f];
        __syncthreads();
        float o = b_l[f];
        #pragma unroll
        for (int k = 0; k < 64; ++k) {
            o = fmaf(mv[g][k], wlT[k * 64 + f], o);
            o = fmaf(xv[g][k], wrT[k * 64 + f], o);
        }
        float m = mish_f(o);
        if (BF) ((unsigned short*)h_out_v)[node * 64 + f] = bf_rne(m);
        else    ((float*)h_out_v)[node * 64 + f] = m;
        __syncthreads();
    }
}

// ---------- ring-3 DMA-staged bf16-MFMA GEMM ----------
// Cp[by][64][N] = A[64][Ksl] * W[Ntile][Ksl]^T.  R6 skeleton (global_load_lds DMA,
// pre-swizzled A source <-> swizzled read, consume-side fp32->bf16 convert) with a
// RING OF 3 buffer sets and issue-2-ahead counted vmcnt: at every consume, 12 loads
// (2 full steps, 48 KB/block) stay in flight; the freed buffer is refilled right
// after the readers-done barrier -> near-continuous issue (anti-starvation test).
template <int KS>
__global__ void __launch_bounds__(256) gemm_ring(
        const unsigned short* __restrict__ Abf, const float* __restrict__ W,
        float* __restrict__ Cp, int N) {
    __shared__ __align__(16) float          Wlds[3][4096];   // 48 KB (fp32 W steps)
    __shared__ __align__(16) unsigned short Alds[3][4096];   // 24 KB (bf16 A steps)
    int t = threadIdx.x;
    int bx = blockIdx.x, by = blockIdx.y;
    int kb0 = (by * NKB) / KS;
    int kb1 = ((by + 1) * NKB) / KS;
    int S = kb1 - kb0;                 // 14 or 15
    int n0 = bx * 64;
    int wv = t >> 6, l = t & 63, l15 = l & 15, hi = l >> 4;

    // staging source pointers (per thread), pre-swizzled granules (R6-verified)
    const float* wsrc[4];
    #pragma unroll
    for (int ii = 0; ii < 4; ++ii) {
        int rloc = wv * 16 + ii * 4 + (l >> 4);         // LDS row 0..63
        int wr = n0 + rloc; if (wr >= N) wr = N - 1;
        int g = (l & 15) ^ ((rloc & 7) << 1);           // 16B granule (4 f32)
        wsrc[ii] = W + (size_t)wr * KDIM + (size_t)kb0 * 64 + g * 4;
    }
    const unsigned short* asrcp[2];
    #pragma unroll
    for (int ii = 0; ii < 2; ++ii) {
        int rloc = wv * 16 + ii * 8 + (l >> 3);         // LDS row 0..63
        int g = (l & 7) ^ (rloc & 7);                   // 16B granule (8 bf16)
        asrcp[ii] = Abf + (size_t)rloc * KDIM + (size_t)kb0 * 64 + g * 8;
    }

    f32x4 acc[4];
    #pragma unroll
    for (int g = 0; g < 4; ++g) acc[g] = (f32x4){0.f, 0.f, 0.f, 0.f};

#define ISSUE(step, buf) do {                                              \
        size_t ko = (size_t)(step) * 64;                                   \
        _Pragma("unroll")                                                  \
        for (int ii = 0; ii < 4; ++ii)                                     \
            gload_lds16(wsrc[ii] + ko, &Wlds[buf][(wv * 16 + ii * 4) * 64]); \
        _Pragma("unroll")                                                  \
        for (int ii = 0; ii < 2; ++ii)                                     \
            gload_lds16(asrcp[ii] + ko, &Alds[buf][(wv * 16 + ii * 8) * 64]); \
    } while (0)

#define MFMAPH(buf) do {                                                   \
        _Pragma("unroll")                                                  \
        for (int s = 0; s < 2; ++s) {                                      \
            int fw = s * 4 + hi;                                           \
            int n = wv * 16 + l15;                                         \
            int g0 = (2 * fw) ^ ((n & 7) << 1);                            \
            f32x4 wlo = *(const f32x4*)&Wlds[buf][n * 64 + g0 * 4];        \
            f32x4 whi = *(const f32x4*)&Wlds[buf][n * 64 + g0 * 4 + 4];    \
            bf16x8 bh;                                                     \
            _Pragma("unroll")                                              \
            for (int j = 0; j < 4; ++j) {                                  \
                bh[j]     = (short)bf_rne(wlo[j]);                         \
                bh[4 + j] = (short)bf_rne(whi[j]);                         \
            }                                                              \
            _Pragma("unroll")                                              \
            for (int g = 0; g < 4; ++g) {                                  \
                int ar = g * 16 + l15;                                     \
                bf16x8 av = *(const bf16x8*)&Alds[buf][ar * 64 + ((fw ^ (ar & 7)) * 8)]; \
                acc[g] = __builtin_amdgcn_mfma_f32_16x16x32_bf16(av, bh, acc[g], 0, 0, 0); \
            }                                                              \
        }                                                                  \
    } while (0)

#define WAIT12() asm volatile("s_waitcnt vmcnt(12)" ::: "memory")
#define WAIT6()  asm volatile("s_waitcnt vmcnt(6)" ::: "memory")
#define WAIT0()  asm volatile("s_waitcnt vmcnt(0)" ::: "memory")
#define RBAR()   asm volatile("s_barrier" ::: "memory")
#define LBAR()   asm volatile("s_waitcnt lgkmcnt(0)\n\ts_barrier" ::: "memory")

    // prologue: fill the ring (S >= 14 always)
    ISSUE(0, 0);
    ISSUE(1, 1);
    ISSUE(2, 2);

    int b = 0;
    for (int s = 0; s < S; ++s) {
        if (s < S - 2) WAIT12();        // step s landed; 12 newer stay in flight
        else if (s == S - 2) WAIT6();
        else WAIT0();
        RBAR();                          // all waves' step-s loads landed
        MFMAPH(b);
        LBAR();                          // all readers done with buf b
        if (s + 3 < S) ISSUE(s + 3, b);  // refill freed buffer immediately
        b = (b == 2) ? 0 : b + 1;
    }

#undef ISSUE
#undef MFMAPH
#undef WAIT12
#undef WAIT6
#undef WAIT0
#undef RBAR
#undef LBAR

    // store partials
    int gn = n0 + wv * 16 + l15;
    if (gn < N) {
        float* cp = Cp + (size_t)by * 64 * N;
        #pragma unroll
        for (int g = 0; g < 4; ++g)
            #pragma unroll
            for (int rr = 0; rr < 4; ++rr)
                cp[(size_t)(g * 16 + hi * 4 + rr) * N + gn] = acc[g][rr];
    }
}

// ---------- reduce partials + bias + mish + bf16 cast (FC1 epilogue) ----------
__global__ void reduce1_kernel(const float* __restrict__ Cp, const float* __restrict__ b,
                               unsigned short* __restrict__ A2) {
    int i4 = (blockIdx.x * 256 + threadIdx.x) * 4;
    if (i4 >= BATCH * N1) return;
    int n = i4 % N1;
    f32x4 acc = *(const f32x4*)(b + n);
    #pragma unroll
    for (int s = 0; s < KSPLIT; ++s)
        acc += *(const f32x4*)(Cp + (size_t)s * BATCH * N1 + i4);
    s16x4 o;
    #pragma unroll
    for (int j = 0; j < 4; ++j) o[j] = (short)bf_rne(mish_f(acc[j]));
    *(s16x4*)(A2 + i4) = o;
}

// ---------- reduce partials + bias (FC2 epilogue) ----------
__global__ void reduce2_kernel(const float* __restrict__ Cp, const float* __restrict__ b,
                               float* __restrict__ C2) {
    int i4 = (blockIdx.x * 256 + threadIdx.x) * 4;
    if (i4 >= BATCH * N2) return;
    int n = i4 % N2;
    f32x4 acc = *(const f32x4*)(b + n);
    #pragma unroll
    for (int s = 0; s < KSPLIT; ++s)
        acc += *(const f32x4*)(Cp + (size_t)s * BATCH * N2 + i4);
    *(f32x4*)(C2 + i4) = acc;
}

// ---------- symmetrize + unit diagonal (C2 L2-resident, bias pre-added) ----------
__global__ void sym_kernel(const float* __restrict__ C2, float* __restrict__ out) {
    int tid = blockIdx.x * 256 + threadIdx.x;
    if (tid >= BATCH * NN * NN) return;
    int j = tid % NN;
    int r = tid / NN;
    int i = r % NN;
    int b = r / NN;
    float v;
    if (i == j) {
        v = 1.0f;
    } else {
        v = 0.5f * (C2[(size_t)b * N2 + i * NN + j] + C2[(size_t)b * N2 + j * NN + i]);
    }
    out[tid] = v;
}

extern "C" void kernel_launch(void* const* d_in, const int* in_sizes, int n_in,
                              void* d_out, int out_size, void* d_ws, size_t ws_size,
                              hipStream_t stream) {
    const float* z     = (const float*)d_in[0];
    const int*   edge  = (const int*)d_in[1];
    const float* w1_l  = (const float*)d_in[3];
    const float* b1_l  = (const float*)d_in[4];
    const float* w1_r  = (const float*)d_in[5];
    const float* w2_l  = (const float*)d_in[6];
    const float* b2_l  = (const float*)d_in[7];
    const float* w2_r  = (const float*)d_in[8];
    const float* fc1_w = (const float*)d_in[9];
    const float* fc1_b = (const float*)d_in[10];
    const float* fc2_w = (const float*)d_in[11];
    const float* fc2_b = (const float*)d_in[12];
    float* out = (float*)d_out;

    char* ws = (char*)d_ws;
    size_t off = 0;
    auto alloc = [&](size_t bytes) {
        void* p = ws + off;
        off = (off + bytes + 255) & ~(size_t)255;
        return p;
    };
    int*            hist      = (int*)alloc(NODES_TOT * 4);
    int*            row_start = (int*)alloc(NODES_TOT * 4);
    int*            cursor    = (int*)alloc(NODES_TOT * 4);
    int*            csr_src   = (int*)alloc((size_t)EDGES * 4);
    float*          h1        = (float*)alloc((size_t)NODES_TOT * 64 * 4);
    unsigned short* A1        = (unsigned short*)alloc((size_t)NODES_TOT * 64 * 2);
    float*          Cp1       = (float*)alloc((size_t)KSPLIT * BATCH * N1 * 4);
    unsigned short* A2        = (unsigned short*)alloc((size_t)BATCH * N1 * 2);
    float*          Cp2       = (float*)alloc((size_t)KSPLIT * BATCH * N2 * 4);
    float*          C2        = (float*)alloc((size_t)BATCH * N2 * 4);

    const int* src = edge;
    const int* dst = edge + EDGES;

    zero_kernel<<<(NODES_TOT + 255) / 256, 256, 0, stream>>>(hist, NODES_TOT);
    hist_kernel<<<(EDGES + 255) / 256, 256, 0, stream>>>(dst, hist);
    scan_kernel<<<1, 1024, 0, stream>>>(hist, row_start, cursor);
    csr_fill_kernel<<<(EDGES + 255) / 256, 256, 0, stream>>>(src, dst, cursor, csr_src);

    conv_kernel<false><<<928, 256, 0, stream>>>(z, csr_src, row_start, hist, w1_l, b1_l, w1_r, h1);
    conv_kernel<true><<<928, 256, 0, stream>>>(h1, csr_src, row_start, hist, w2_l, b2_l, w2_r, A1);

    // FC1: partials over 8 k-splits, then fused reduce+bias+mish+cast
    gemm_ring<KSPLIT><<<dim3(N1 / 64, KSPLIT), 256, 0, stream>>>(A1, fc1_w, Cp1, N1);
    reduce1_kernel<<<(BATCH * N1 / 4 + 255) / 256, 256, 0, stream>>>(Cp1, fc1_b, A2);

    // FC2: partials over 8 k-splits
    gemm_ring<KSPLIT><<<dim3((N2 + 63) / 64, KSPLIT), 256, 0, stream>>>(A2, fc2_w, Cp2, N2);
    reduce2_kernel<<<(BATCH * N2 / 4 + 255) / 256, 256, 0, stream>>>(Cp2, fc2_b, C2);

    sym_kernel<<<(BATCH * NN * NN + 255) / 256, 256, 0, stream>>>(C2, out);
}